// Round 2
// baseline (1949.986 us; speedup 1.0000x reference)
//
#include <hip/hip_runtime.h>
#include <hip/hip_bf16.h>

typedef __hip_bfloat16 bf16;

#define B_   8
#define S_   512
#define D_   1024
#define H_   16
#define HD_  64
#define FF_  4096
#define ROWS (B_ * S_)   // 4096

__device__ __forceinline__ float bf2f(unsigned short u) {
    union { unsigned int i; float f; } v; v.i = ((unsigned int)u) << 16; return v.f;
}
__device__ __forceinline__ unsigned short f2bfu(float f) {
    bf16 h = __float2bfloat16(f);
    return *reinterpret_cast<unsigned short*>(&h);
}
// load element i from p, which is fp32 if f32 else bf16
__device__ __forceinline__ float ldsel(const void* p, size_t i, bool f32) {
    return f32 ? ((const float*)p)[i]
               : __bfloat162float(((const bf16*)p)[i]);
}
__device__ __forceinline__ float gelu_exact(float x) {
    return 0.5f * x * (1.f + erff(x * 0.70710678118654752440f));
}

// ---------------- LayerNorm: one block per row, D=1024, 256 threads ----------
// x_ws: 1 => x is ws bf16; 0 => x is d_in (dtype from probe)
__global__ __launch_bounds__(256) void ln_kernel(const void* __restrict__ x,
                                                 const void* __restrict__ gam,
                                                 const void* __restrict__ bet,
                                                 bf16* __restrict__ out,
                                                 int x_ws,
                                                 const unsigned short* __restrict__ probe) {
    bool pf32 = (probe[0] == 0);          // d_in tensors are fp32?
    bool xf32 = (!x_ws) && pf32;
    int row = blockIdx.x;
    int tid = threadIdx.x;
    size_t rb = (size_t)row * D_;
    float v[4];
#pragma unroll
    for (int i = 0; i < 4; ++i) v[i] = ldsel(x, rb + tid + i * 256, xf32);
    float s  = v[0] + v[1] + v[2] + v[3];
    float s2 = v[0] * v[0] + v[1] * v[1] + v[2] * v[2] + v[3] * v[3];
#pragma unroll
    for (int off = 32; off > 0; off >>= 1) {
        s  += __shfl_down(s, off);
        s2 += __shfl_down(s2, off);
    }
    __shared__ float red[8];
    int wv = tid >> 6, ln = tid & 63;
    if (ln == 0) { red[wv] = s; red[4 + wv] = s2; }
    __syncthreads();
    s  = red[0] + red[1] + red[2] + red[3];
    s2 = red[4] + red[5] + red[6] + red[7];
    float mean = s * (1.f / 1024.f);
    float var  = s2 * (1.f / 1024.f) - mean * mean;
    float rstd = rsqrtf(var + 1e-5f);
#pragma unroll
    for (int i = 0; i < 4; ++i) {
        int c = tid + i * 256;
        float g = ldsel(gam, c, pf32), b = ldsel(bet, c, pf32);
        out[rb + c] = __float2bfloat16((v[i] - mean) * rstd * g + b);
    }
}

// ---------------- GEMM: C[M,N] = A[M,K](ws bf16) * Bw(d_in) (+epilogue) ------
// B addressing: elem = (n>>6)*sH + k*sK + (n&63)
//   row-major [K,N]:   sK=N,   sH=64
//   per-head [H,D,HD]: sK=HD,  sH=D*HD
// mode 0: plain; mode 1: +bias +resid; mode 2: +bias, gelu
// resid_ws: 1 => resid is ws bf16; 0 => resid is d_in (probe dtype)
// store: outFinal (d_out, probe dtype) if non-null, else outWS (ws bf16)
__global__ __launch_bounds__(256) void gemm_kernel(
    const bf16* __restrict__ A, const void* __restrict__ Bw,
    int M, int N, int K, int sK, int sH,
    const void* __restrict__ bias,
    const void* __restrict__ resid, int resid_ws,
    bf16* __restrict__ outWS, void* __restrict__ outFinal, int mode,
    const unsigned short* __restrict__ probe) {
    bool pf32 = (probe[0] == 0);
    __shared__ float As[16][68];
    __shared__ float Bs[16][68];
    int tid = threadIdx.x;
    int n0 = blockIdx.x * 64, m0 = blockIdx.y * 64;
    int tx = tid & 15, ty = tid >> 4;
    float acc[4][4];
#pragma unroll
    for (int i = 0; i < 4; ++i)
#pragma unroll
        for (int j = 0; j < 4; ++j) acc[i][j] = 0.f;

    int am = tid >> 2;         // 0..63 (m within tile)
    int ak = (tid & 3) * 4;    // 0,4,8,12 (k within tile)
    int bk = tid >> 4;         // 0..15 (k within tile)
    int bn = (tid & 15) * 4;   // 0..60 (n within tile)
    size_t Bhead = (size_t)(n0 >> 6) * sH;

    for (int k0 = 0; k0 < K; k0 += 16) {
        __syncthreads();
        ushort4 av = *reinterpret_cast<const ushort4*>(A + (size_t)(m0 + am) * K + k0 + ak);
        As[ak + 0][am] = bf2f(av.x); As[ak + 1][am] = bf2f(av.y);
        As[ak + 2][am] = bf2f(av.z); As[ak + 3][am] = bf2f(av.w);
        size_t be = Bhead + (size_t)(k0 + bk) * sK + bn;
        if (pf32) {
            float4 bv = *reinterpret_cast<const float4*>((const float*)Bw + be);
            Bs[bk][bn + 0] = bv.x; Bs[bk][bn + 1] = bv.y;
            Bs[bk][bn + 2] = bv.z; Bs[bk][bn + 3] = bv.w;
        } else {
            ushort4 bv = *reinterpret_cast<const ushort4*>((const bf16*)Bw + be);
            Bs[bk][bn + 0] = bf2f(bv.x); Bs[bk][bn + 1] = bf2f(bv.y);
            Bs[bk][bn + 2] = bf2f(bv.z); Bs[bk][bn + 3] = bf2f(bv.w);
        }
        __syncthreads();
#pragma unroll
        for (int kk = 0; kk < 16; ++kk) {
            float4 a = *reinterpret_cast<const float4*>(&As[kk][ty * 4]);
            float4 b = *reinterpret_cast<const float4*>(&Bs[kk][tx * 4]);
            float aa[4] = {a.x, a.y, a.z, a.w};
            float bb[4] = {b.x, b.y, b.z, b.w};
#pragma unroll
            for (int i = 0; i < 4; ++i)
#pragma unroll
                for (int j = 0; j < 4; ++j) acc[i][j] += aa[i] * bb[j];
        }
    }
#pragma unroll
    for (int i = 0; i < 4; ++i) {
        int m = m0 + ty * 4 + i;
#pragma unroll
        for (int jj = 0; jj < 4; ++jj) {
            int n = n0 + tx * 4 + jj;
            size_t idx = (size_t)m * N + n;
            float c = acc[i][jj];
            if (mode == 1) {
                c += ldsel(bias, n, pf32);
                c += resid_ws ? __bfloat162float(((const bf16*)resid)[idx])
                              : ldsel(resid, idx, pf32);
            } else if (mode == 2) {
                c = gelu_exact(c + ldsel(bias, n, pf32));
            }
            if (outFinal) {
                if (pf32) ((float*)outFinal)[idx] = c;
                else      ((bf16*)outFinal)[idx] = __float2bfloat16(c);
            } else {
                outWS[idx] = __float2bfloat16(c);
            }
        }
    }
}

// ---------------- Flash attention, causal, BQ=BK=64, HD=64 ------------------
// Q,K,V,O: ws bf16, layout [B, S, H, HD] row-major (row stride 1024)
__global__ __launch_bounds__(256) void attn_kernel(const bf16* __restrict__ Qg,
                                                   const bf16* __restrict__ Kg,
                                                   const bf16* __restrict__ Vg,
                                                   bf16* __restrict__ Og) {
    int qb = blockIdx.x;          // 0..7
    int bh = blockIdx.y;          // 0..127
    int b = bh >> 4, h = bh & 15;
    int tid = threadIdx.x;
    int q = tid >> 2;             // 0..63 query row within tile
    int j = tid & 3;              // 0..3  sub-slice

    __shared__ float Qs[64][65];
    __shared__ float Ks[64][65];
    __shared__ float Vs[64][65];
    __shared__ float Ps[64][65];

    size_t base = ((size_t)(b * S_) * H_ + h) * HD_;
    {
        size_t qoff = base + (size_t)(qb * 64) * 1024;
#pragma unroll
        for (int it = 0; it < 4; ++it) {
            int lin = tid + it * 256;
            int r = lin >> 4, c = (lin & 15) * 4;
            ushort4 qv = *reinterpret_cast<const ushort4*>(Qg + qoff + (size_t)r * 1024 + c);
            Qs[r][c + 0] = bf2f(qv.x) * 0.125f; Qs[r][c + 1] = bf2f(qv.y) * 0.125f;
            Qs[r][c + 2] = bf2f(qv.z) * 0.125f; Qs[r][c + 3] = bf2f(qv.w) * 0.125f;
        }
    }
    float Ov[16];
#pragma unroll
    for (int i = 0; i < 16; ++i) Ov[i] = 0.f;
    float mrow = -1e30f, lrow = 0.f;

    for (int kb = 0; kb <= qb; ++kb) {
        __syncthreads();   // protect K/V/P reuse from previous iteration
        size_t koff = base + (size_t)(kb * 64) * 1024;
#pragma unroll
        for (int it = 0; it < 4; ++it) {
            int lin = tid + it * 256;
            int r = lin >> 4, c = (lin & 15) * 4;
            ushort4 kv = *reinterpret_cast<const ushort4*>(Kg + koff + (size_t)r * 1024 + c);
            Ks[r][c + 0] = bf2f(kv.x); Ks[r][c + 1] = bf2f(kv.y);
            Ks[r][c + 2] = bf2f(kv.z); Ks[r][c + 3] = bf2f(kv.w);
            ushort4 vv = *reinterpret_cast<const ushort4*>(Vg + koff + (size_t)r * 1024 + c);
            Vs[r][c + 0] = bf2f(vv.x); Vs[r][c + 1] = bf2f(vv.y);
            Vs[r][c + 2] = bf2f(vv.z); Vs[r][c + 3] = bf2f(vv.w);
        }
        __syncthreads();

        float sc[16];
#pragma unroll
        for (int tt = 0; tt < 16; ++tt) sc[tt] = 0.f;
        for (int d = 0; d < 64; ++d) {
            float qd = Qs[q][d];
#pragma unroll
            for (int tt = 0; tt < 16; ++tt) sc[tt] += qd * Ks[j * 16 + tt][d];
        }
        if (kb == qb) {
#pragma unroll
            for (int tt = 0; tt < 16; ++tt)
                if (j * 16 + tt > q) sc[tt] = -1e30f;
        }
        float mt = sc[0];
#pragma unroll
        for (int tt = 1; tt < 16; ++tt) mt = fmaxf(mt, sc[tt]);
        mt = fmaxf(mt, __shfl_xor(mt, 1));
        mt = fmaxf(mt, __shfl_xor(mt, 2));
        float mnew  = fmaxf(mrow, mt);
        float alpha = __expf(mrow - mnew);
        float psum = 0.f;
#pragma unroll
        for (int tt = 0; tt < 16; ++tt) {
            float p = __expf(sc[tt] - mnew);
            sc[tt] = p; psum += p;
        }
        psum += __shfl_xor(psum, 1);
        psum += __shfl_xor(psum, 2);
        lrow = lrow * alpha + psum;
        mrow = mnew;
#pragma unroll
        for (int i = 0; i < 16; ++i) Ov[i] *= alpha;
#pragma unroll
        for (int tt = 0; tt < 16; ++tt) Ps[q][j * 16 + tt] = sc[tt];
        __syncthreads();
        for (int t = 0; t < 64; ++t) {
            float p = Ps[q][t];
#pragma unroll
            for (int eo = 0; eo < 16; ++eo) Ov[eo] += p * Vs[t][j * 16 + eo];
        }
    }
    float rl = 1.f / lrow;
    size_t ooff = base + (size_t)(qb * 64 + q) * 1024 + j * 16;
#pragma unroll
    for (int v4 = 0; v4 < 4; ++v4) {
        ushort4 o;
        o.x = f2bfu(Ov[v4 * 4 + 0] * rl); o.y = f2bfu(Ov[v4 * 4 + 1] * rl);
        o.z = f2bfu(Ov[v4 * 4 + 2] * rl); o.w = f2bfu(Ov[v4 * 4 + 3] * rl);
        *reinterpret_cast<ushort4*>(Og + ooff + v4 * 4) = o;
    }
}

extern "C" void kernel_launch(void* const* d_in, const int* in_sizes, int n_in,
                              void* d_out, int out_size, void* d_ws, size_t ws_size,
                              hipStream_t stream) {
    const void* x   = d_in[0];
    const void* Wq  = d_in[1];
    const void* Wk  = d_in[2];
    const void* Wv  = d_in[3];
    const void* Wo  = d_in[4];
    const void* bo  = d_in[5];
    const void* g1  = d_in[6];
    const void* b1  = d_in[7];
    const void* g2  = d_in[8];
    const void* b2  = d_in[9];
    const void* W1  = d_in[10];
    const void* bf1 = d_in[11];
    const void* W2  = d_in[12];
    const void* bf2 = d_in[13];
    const unsigned short* probe = (const unsigned short*)g1;  // all-ones tensor

    // bf16 workspace, 28M elems = 56 MB total
    bf16* ws = (bf16*)d_ws;
    const size_t MROW = (size_t)ROWS * D_;   // 4M elems
    bf16* h     = ws;              // [0,4M)
    bf16* Qb    = ws + 1 * MROW;   // [4M,8M)
    bf16* Kb    = ws + 2 * MROW;   // [8M,12M)
    bf16* Vb    = ws + 3 * MROW;   // [12M,16M)
    bf16* ctx   = ws;              // reuse h slot
    bf16* cache = ws + 1 * MROW;   // reuse Qb slot
    bf16* h2    = ws + 2 * MROW;   // reuse Kb slot
    bf16* ff1   = ws + 3 * MROW;   // [12M,28M), 16M elems (Vb dead)

    // 1. LN1
    ln_kernel<<<ROWS, 256, 0, stream>>>(x, g1, b1, h, 0, probe);
    // 2. QKV projections (per-head weights [H,D,HD]: sK=HD, sH=D*HD)
    dim3 gQ(D_ / 64, ROWS / 64);
    gemm_kernel<<<gQ, 256, 0, stream>>>(h, Wq, ROWS, D_, D_, HD_, D_ * HD_,
                                        nullptr, nullptr, 0, Qb, nullptr, 0, probe);
    gemm_kernel<<<gQ, 256, 0, stream>>>(h, Wk, ROWS, D_, D_, HD_, D_ * HD_,
                                        nullptr, nullptr, 0, Kb, nullptr, 0, probe);
    gemm_kernel<<<gQ, 256, 0, stream>>>(h, Wv, ROWS, D_, D_, HD_, D_ * HD_,
                                        nullptr, nullptr, 0, Vb, nullptr, 0, probe);
    // 3. attention -> ctx ([B,S,H,HD] == [4096,1024])
    dim3 gA(S_ / 64, B_ * H_);
    attn_kernel<<<gA, 256, 0, stream>>>(Qb, Kb, Vb, ctx);
    // 4. Wo proj + bias + residual(x) -> cache
    gemm_kernel<<<gQ, 256, 0, stream>>>(ctx, Wo, ROWS, D_, D_, D_, 64,
                                        bo, x, 0, cache, nullptr, 1, probe);
    // 5. LN2 (input from ws)
    ln_kernel<<<ROWS, 256, 0, stream>>>(cache, g2, b2, h2, 1, probe);
    // 6. FF1 + bias + gelu -> ff1
    dim3 gF1(FF_ / 64, ROWS / 64);
    gemm_kernel<<<gF1, 256, 0, stream>>>(h2, W1, ROWS, FF_, D_, FF_, 64,
                                         bf1, nullptr, 0, ff1, nullptr, 2, probe);
    // 7. FF2 + bias + residual(cache) -> d_out (probe dtype)
    gemm_kernel<<<gQ, 256, 0, stream>>>(ff1, W2, ROWS, D_, FF_, D_, 64,
                                        bf2, cache, 1, nullptr, d_out, 1, probe);
}